// Round 1
// baseline (217.817 us; speedup 1.0000x reference)
//
#include <hip/hip_runtime.h>

#define S 512
#define UNITS 9
#define IPB 4        // i-rows per block
#define RPT 8        // consecutive j per thread
#define BLOCK 256
#define BCHUNK 10    // batches per block

// Gather inputs[b, j, j, 0] (stride 513 floats) into compact diag[b*S + j].
__global__ void diag_extract_kernel(const float* __restrict__ in,
                                    float* __restrict__ diag, int BS) {
    int idx = blockIdx.x * blockDim.x + threadIdx.x;
    if (idx < BS) {
        int b = idx >> 9;        // / 512
        int j = idx & (S - 1);
        diag[idx] = in[(size_t)b * S * S + (size_t)j * (S + 1)];
    }
}

__global__ __launch_bounds__(BLOCK, 4) void cnn_main_kernel(
        const float* __restrict__ w, const float* __restrict__ bv,
        const float* __restrict__ diag, const float* __restrict__ raw_in,
        float* __restrict__ out, int B) {
    __shared__ __align__(16) float sdiag[S + 8];   // padded with zeros for j+t >= S

    const int group = blockIdx.x & ((S / IPB) - 1);   // 0..127
    const int chunk = blockIdx.x / (S / IPB);
    const int row   = threadIdx.x >> 6;               // 0..3  (i uniform per wave)
    const int lane  = threadIdx.x & 63;
    const int i     = group * IPB + row;
    const int j0    = lane * RPT;

    // ---- load w fragment into registers (once; reused across BCHUNK batches) ----
    float wv[RPT * UNITS];                            // 72 floats
    {
        // element offset (i*S + j0)*9 = i*4608 + 72*lane -> byte offset 16B-aligned
        const float4* ws4 = reinterpret_cast<const float4*>(
            w + (size_t)(i * S + j0) * UNITS);
        #pragma unroll
        for (int q = 0; q < RPT * UNITS / 4; ++q) {   // 18 aligned float4 loads
            float4 v = ws4[q];
            wv[4*q+0] = v.x; wv[4*q+1] = v.y; wv[4*q+2] = v.z; wv[4*q+3] = v.w;
        }
    }
    // valid_i mask: zero wv where i + t/3 >= S  (only i = 510, 511 affected)
    if (i >= S - 2) {
        const int tmax = (i == S - 1) ? 3 : 6;        // first invalid t
        #pragma unroll
        for (int k = 0; k < RPT * UNITS; ++k)
            if ((k % UNITS) >= tmax) wv[k] = 0.f;
    }

    // ---- bias: per-j sum of 9 consecutive b values (UNMASKED per reference) ----
    float bias[RPT];
    {
        float bb[RPT * UNITS];
        const float4* bs4 = reinterpret_cast<const float4*>(
            bv + (size_t)(i * S + j0) * UNITS);
        #pragma unroll
        for (int q = 0; q < RPT * UNITS / 4; ++q) {
            float4 v = bs4[q];
            bb[4*q+0] = v.x; bb[4*q+1] = v.y; bb[4*q+2] = v.z; bb[4*q+3] = v.w;
        }
        #pragma unroll
        for (int r = 0; r < RPT; ++r) {
            float s = 0.f;
            #pragma unroll
            for (int t = 0; t < UNITS; ++t) s += bb[r * UNITS + t];
            bias[r] = s;
        }
    }

    const int b0 = chunk * BCHUNK;
    for (int bb = 0; bb < BCHUNK; ++bb) {
        const int b = b0 + bb;
        if (b >= B) break;                            // uniform across block

        __syncthreads();                              // protect sdiag from prev iter readers
        for (int idx = threadIdx.x; idx < S + 8; idx += BLOCK) {
            float v = 0.f;
            if (idx < S)
                v = diag ? diag[(size_t)b * S + idx]
                         : raw_in[(size_t)b * S * S + (size_t)idx * (S + 1)];
            sdiag[idx] = v;
        }
        __syncthreads();

        // 16 diag values cover j0..j0+15 (j0 multiple of 8 -> 32B aligned)
        float dv[RPT + UNITS - 1];                    // 16
        const float4* d4 = reinterpret_cast<const float4*>(&sdiag[j0]);
        #pragma unroll
        for (int q = 0; q < 4; ++q) {                 // 4x ds_read_b128
            float4 v = d4[q];
            dv[4*q+0] = v.x; dv[4*q+1] = v.y; dv[4*q+2] = v.z; dv[4*q+3] = v.w;
        }

        float res[RPT];
        #pragma unroll
        for (int r = 0; r < RPT; ++r) {
            float acc = 0.f;
            #pragma unroll
            for (int t = 0; t < UNITS; ++t)
                acc = fmaf(dv[r + t], wv[r * UNITS + t], acc);
            res[r] = fmaf(acc, (float)UNITS, bias[r]);
        }

        float4* o4 = reinterpret_cast<float4*>(
            out + (size_t)b * S * S + (size_t)i * S + j0);
        o4[0] = make_float4(res[0], res[1], res[2], res[3]);
        o4[1] = make_float4(res[4], res[5], res[6], res[7]);
    }
}

extern "C" void kernel_launch(void* const* d_in, const int* in_sizes, int n_in,
                              void* d_out, int out_size, void* d_ws, size_t ws_size,
                              hipStream_t stream) {
    const float* in = (const float*)d_in[0];
    const float* w  = (const float*)d_in[1];
    const float* bv = (const float*)d_in[2];
    float* out      = (float*)d_out;

    const int B  = in_sizes[0] / (S * S);   // 100
    const int BS = B * S;

    float* diag = nullptr;
    if (ws_size >= (size_t)BS * sizeof(float)) {
        diag = (float*)d_ws;
        diag_extract_kernel<<<(BS + 255) / 256, 256, 0, stream>>>(in, diag, BS);
    }

    const int nchunk = (B + BCHUNK - 1) / BCHUNK;
    dim3 grid((S / IPB) * nchunk);
    cnn_main_kernel<<<grid, BLOCK, 0, stream>>>(w, bv, diag, in, out, B);
}

// Round 2
// 207.266 us; speedup vs baseline: 1.0509x; 1.0509x over previous
//
#include <hip/hip_runtime.h>

#define S 512
#define SP 520       // padded diag row: 512 values + 8 zeros (so j+t reads never wrap)
#define UNITS 9
#define BLOCK 256
#define BCHUNK 10    // batches per block

// Gather inputs[b, j, j, 0] into padded compact diag[b*SP + j]; zero the pad.
__global__ void diag_extract_kernel(const float* __restrict__ in,
                                    float* __restrict__ diag, int B) {
    int idx = blockIdx.x * blockDim.x + threadIdx.x;
    if (idx < B * SP) {
        int b = idx / SP;
        int j = idx - b * SP;
        diag[idx] = (j < S) ? in[(size_t)b * S * S + (size_t)j * (S + 1)] : 0.f;
    }
}

// One wave per i-row (4 rows/block). Thread owns j = 4*lane and j = 256+4*lane,
// so each dwordx4 store is fully contiguous across the wave (full-line writes).
template<bool USE_WS>
__global__ __launch_bounds__(BLOCK) void cnn_main_kernel(
        const float* __restrict__ w, const float* __restrict__ bv,
        const float* __restrict__ diag, const float* __restrict__ raw_in,
        float* __restrict__ out, int B) {
    __shared__ __align__(16) float sdiag[USE_WS ? 1 : SP];

    const int group = blockIdx.x & ((S / 4) - 1);    // 0..127
    const int chunk = blockIdx.x >> 7;
    const int row   = threadIdx.x >> 6;              // 0..3 (wave-uniform)
    const int lane  = threadIdx.x & 63;
    const int i     = group * 4 + row;
    const int jA    = 4 * lane;                      // chunk A: j in [0,256)
    const int jB    = 256 + 4 * lane;                // chunk B: j in [256,512)

    // ---- w fragments into registers (reused across BCHUNK batches) ----
    float wv[72];                                    // [0..35]=A, [36..71]=B
    {
        const float4* wa = reinterpret_cast<const float4*>(w + (size_t)(i * S + jA) * UNITS);
        const float4* wb = reinterpret_cast<const float4*>(w + (size_t)(i * S + jB) * UNITS);
        #pragma unroll
        for (int q = 0; q < 9; ++q) {                // byte offset 144*lane: 16B aligned
            float4 va = wa[q], vb = wb[q];
            wv[4*q+0] = va.x; wv[4*q+1] = va.y; wv[4*q+2] = va.z; wv[4*q+3] = va.w;
            wv[36+4*q+0] = vb.x; wv[36+4*q+1] = vb.y; wv[36+4*q+2] = vb.z; wv[36+4*q+3] = vb.w;
        }
    }
    // valid_i: zero w where i + t/3 >= S (only i = 510, 511)
    if (i >= S - 2) {
        const int tmax = (i == S - 1) ? 3 : 6;
        #pragma unroll
        for (int h = 0; h < 2; ++h)
            #pragma unroll
            for (int r = 0; r < 4; ++r)
                #pragma unroll
                for (int t = 0; t < UNITS; ++t)
                    if (t >= tmax) wv[36*h + r*UNITS + t] = 0.f;
    }

    // ---- bias: per-j sum of 9 consecutive b values (unmasked per reference) ----
    float bias[8];                                   // [0..3]=A, [4..7]=B
    {
        float tmp[72];
        const float4* ba = reinterpret_cast<const float4*>(bv + (size_t)(i * S + jA) * UNITS);
        const float4* bb = reinterpret_cast<const float4*>(bv + (size_t)(i * S + jB) * UNITS);
        #pragma unroll
        for (int q = 0; q < 9; ++q) {
            float4 va = ba[q], vb = bb[q];
            tmp[4*q+0] = va.x; tmp[4*q+1] = va.y; tmp[4*q+2] = va.z; tmp[4*q+3] = va.w;
            tmp[36+4*q+0] = vb.x; tmp[36+4*q+1] = vb.y; tmp[36+4*q+2] = vb.z; tmp[36+4*q+3] = vb.w;
        }
        #pragma unroll
        for (int r = 0; r < 8; ++r) {
            float s = 0.f;
            #pragma unroll
            for (int t = 0; t < UNITS; ++t) s += tmp[r * UNITS + t];
            bias[r] = s;
        }
    }

    const int b0 = chunk * BCHUNK;
    for (int bb = 0; bb < BCHUNK; ++bb) {
        const int b = b0 + bb;
        if (b >= B) break;                           // uniform

        const float* p;
        if (USE_WS) {
            p = diag + (size_t)b * SP;
        } else {
            __syncthreads();
            for (int idx = threadIdx.x; idx < SP; idx += BLOCK)
                sdiag[idx] = (idx < S) ? raw_in[(size_t)b * S * S + (size_t)idx * (S + 1)] : 0.f;
            __syncthreads();
            p = sdiag;
        }

        // 12 diag values per chunk: 3 aligned float4 loads each
        float dA[12], dB[12];
        {
            const float4* pa = reinterpret_cast<const float4*>(p + jA);
            const float4* pb = reinterpret_cast<const float4*>(p + jB);
            #pragma unroll
            for (int q = 0; q < 3; ++q) {
                float4 va = pa[q], vb = pb[q];
                dA[4*q+0] = va.x; dA[4*q+1] = va.y; dA[4*q+2] = va.z; dA[4*q+3] = va.w;
                dB[4*q+0] = vb.x; dB[4*q+1] = vb.y; dB[4*q+2] = vb.z; dB[4*q+3] = vb.w;
            }
        }

        float4 resA, resB;
        float* rA = &resA.x; float* rB = &resB.x;
        #pragma unroll
        for (int r = 0; r < 4; ++r) {
            float accA = 0.f, accB = 0.f;
            #pragma unroll
            for (int t = 0; t < UNITS; ++t) {
                accA = fmaf(dA[r + t], wv[r * UNITS + t], accA);
                accB = fmaf(dB[r + t], wv[36 + r * UNITS + t], accB);
            }
            rA[r] = fmaf(accA, (float)UNITS, bias[r]);
            rB[r] = fmaf(accB, (float)UNITS, bias[4 + r]);
        }

        float* orow = out + (size_t)b * S * S + (size_t)i * S;
        *reinterpret_cast<float4*>(orow + jA) = resA;   // wave: 1024B contiguous
        *reinterpret_cast<float4*>(orow + jB) = resB;   // wave: 1024B contiguous
    }
}

extern "C" void kernel_launch(void* const* d_in, const int* in_sizes, int n_in,
                              void* d_out, int out_size, void* d_ws, size_t ws_size,
                              hipStream_t stream) {
    const float* in = (const float*)d_in[0];
    const float* w  = (const float*)d_in[1];
    const float* bv = (const float*)d_in[2];
    float* out      = (float*)d_out;

    const int B = in_sizes[0] / (S * S);   // 100
    const int nchunk = (B + BCHUNK - 1) / BCHUNK;
    dim3 grid((S / 4) * nchunk);

    if (ws_size >= (size_t)B * SP * sizeof(float)) {
        float* diag = (float*)d_ws;
        diag_extract_kernel<<<(B * SP + 255) / 256, 256, 0, stream>>>(in, diag, B);
        cnn_main_kernel<true><<<grid, BLOCK, 0, stream>>>(w, bv, diag, in, out, B);
    } else {
        cnn_main_kernel<false><<<grid, BLOCK, 0, stream>>>(w, bv, nullptr, in, out, B);
    }
}

// Round 3
// 198.783 us; speedup vs baseline: 1.0958x; 1.0427x over previous
//
#include <hip/hip_runtime.h>

#define S 512
#define SP 520        // padded compact diag row (8 trailing zeros)
#define UNITS 9
#define BCHUNK 10     // batches per main block

// ---------------- workspace layout ----------------
// [0x00000            ) diag     : B*SP floats   (208 KB)
// [0x40000            ) w_t      : 9*S*S floats  (9.44 MB)  w_t[t*S*S + i*S + j], valid_i pre-applied
// [0x40000 + 9*S*S*4  ) bias_sum : S*S floats    (1.05 MB)
#define WT_OFF   (0x40000)
#define BIAS_OFF (WT_OFF + UNITS * S * S * 4)
#define WS_NEED  (BIAS_OFF + S * S * 4)

// One block per i-row: transpose+mask w, sum bias, and (grid-stride) extract diag.
__global__ __launch_bounds__(256) void prep_kernel(
        const float* __restrict__ w, const float* __restrict__ bv,
        const float* __restrict__ in, float* __restrict__ diag,
        float* __restrict__ w_t, float* __restrict__ bias_sum, int B) {
    __shared__ __align__(16) float sw[S * UNITS];   // 18 KB
    __shared__ __align__(16) float sb[S * UNITS];   // 18 KB

    const int i   = blockIdx.x;
    const int tid = threadIdx.x;

    // diag extraction, spread across the whole grid (512*256 threads > 100*520)
    {
        int idx = blockIdx.x * 256 + tid;
        if (idx < B * SP) {
            int b = idx / SP;
            int j = idx - b * SP;
            diag[idx] = (j < S) ? in[(size_t)b * S * S + (size_t)j * (S + 1)] : 0.f;
        }
    }

    // stage w row + b row into LDS, fully coalesced float4
    {
        const float4* wr = reinterpret_cast<const float4*>(w + (size_t)i * S * UNITS);
        const float4* br = reinterpret_cast<const float4*>(bv + (size_t)i * S * UNITS);
        float4* sw4 = reinterpret_cast<float4*>(sw);
        float4* sb4 = reinterpret_cast<float4*>(sb);
        for (int q = tid; q < S * UNITS / 4; q += 256) {   // 1152 float4 each
            sw4[q] = wr[q];
            sb4[q] = br[q];
        }
    }
    __syncthreads();

    const int tmax = min(UNITS, 3 * (S - i));   // first invalid t (i=510 -> 6, i=511 -> 3)
    for (int j = tid; j < S; j += 256) {
        float s = 0.f;
        #pragma unroll
        for (int t = 0; t < UNITS; ++t) s += sb[j * UNITS + t];   // stride-9: conflict-free
        bias_sum[(size_t)i * S + j] = s;
        #pragma unroll
        for (int t = 0; t < UNITS; ++t) {
            float v = (t < tmax) ? sw[j * UNITS + t] : 0.f;
            w_t[(size_t)t * S * S + (size_t)i * S + j] = v;       // coalesced dword store
        }
    }
}

// 2 i-rows per block, 128 threads per row, each thread owns one float4 of output.
__global__ __launch_bounds__(256) void cnn_main_kernel(
        const float* __restrict__ w_t, const float* __restrict__ bias_sum,
        const float* __restrict__ diag, float* __restrict__ out, int B) {
    const int group = blockIdx.x & ((S / 2) - 1);   // 0..255 -> i pair
    const int chunk = blockIdx.x >> 8;              // batch chunk
    const int r     = threadIdx.x >> 7;             // 0..1
    const int jl    = threadIdx.x & 127;
    const int i     = group * 2 + r;
    const int j0    = jl * 4;

    // ---- registers: 9 coalesced float4 loads of premasked w, 1 float4 bias ----
    float4 wt[UNITS];
    #pragma unroll
    for (int t = 0; t < UNITS; ++t)
        wt[t] = *reinterpret_cast<const float4*>(
            w_t + (size_t)t * S * S + (size_t)i * S + j0);
    const float4 bias = *reinterpret_cast<const float4*>(
        bias_sum + (size_t)i * S + j0);

    const float* wv = reinterpret_cast<const float*>(wt);   // wv[t*4 + r]

    const int b0 = chunk * BCHUNK;
    for (int bb = 0; bb < BCHUNK; ++bb) {
        const int b = b0 + bb;
        if (b >= B) break;                          // uniform

        // 12 diag values: 3 overllapping-across-lanes but per-inst coalesced float4
        float dv[12];
        {
            const float4* p = reinterpret_cast<const float4*>(diag + (size_t)b * SP + j0);
            #pragma unroll
            for (int q = 0; q < 3; ++q) {
                float4 v = p[q];
                dv[4*q+0] = v.x; dv[4*q+1] = v.y; dv[4*q+2] = v.z; dv[4*q+3] = v.w;
            }
        }

        float4 res;
        float* rp = &res.x;
        const float* bp = &bias.x;
        #pragma unroll
        for (int k = 0; k < 4; ++k) {
            float acc = 0.f;
            #pragma unroll
            for (int t = 0; t < UNITS; ++t)
                acc = fmaf(dv[k + t], wv[t * 4 + k], acc);
            rp[k] = fmaf(acc, (float)UNITS, bp[k]);
        }

        // full-line store: wave writes 1024B contiguous
        *reinterpret_cast<float4*>(out + (size_t)b * S * S + (size_t)i * S + j0) = res;
    }
}

// ---- fallback (ws too small): self-contained, reads raw input via LDS ----
__global__ __launch_bounds__(256) void cnn_fallback_kernel(
        const float* __restrict__ w, const float* __restrict__ bv,
        const float* __restrict__ raw_in, float* __restrict__ out, int B) {
    __shared__ __align__(16) float sdiag[SP];
    const int group = blockIdx.x & ((S / 2) - 1);
    const int chunk = blockIdx.x >> 8;
    const int r     = threadIdx.x >> 7;
    const int jl    = threadIdx.x & 127;
    const int i     = group * 2 + r;
    const int j0    = jl * 4;

    float wv[4 * UNITS];
    {
        const float4* ws4 = reinterpret_cast<const float4*>(w + (size_t)(i * S + j0) * UNITS);
        #pragma unroll
        for (int q = 0; q < 9; ++q) {
            float4 v = ws4[q];
            wv[4*q] = v.x; wv[4*q+1] = v.y; wv[4*q+2] = v.z; wv[4*q+3] = v.w;
        }
    }
    if (i >= S - 2) {
        const int tmax = 3 * (S - i);
        #pragma unroll
        for (int k = 0; k < 4; ++k)
            #pragma unroll
            for (int t = 0; t < UNITS; ++t)
                if (t >= tmax) wv[k * UNITS + t] = 0.f;
    }
    float bias[4];
    {
        float tmp[4 * UNITS];
        const float4* bs4 = reinterpret_cast<const float4*>(bv + (size_t)(i * S + j0) * UNITS);
        #pragma unroll
        for (int q = 0; q < 9; ++q) {
            float4 v = bs4[q];
            tmp[4*q] = v.x; tmp[4*q+1] = v.y; tmp[4*q+2] = v.z; tmp[4*q+3] = v.w;
        }
        #pragma unroll
        for (int k = 0; k < 4; ++k) {
            float s = 0.f;
            #pragma unroll
            for (int t = 0; t < UNITS; ++t) s += tmp[k * UNITS + t];
            bias[k] = s;
        }
    }
    const int b0 = chunk * BCHUNK;
    for (int bb = 0; bb < BCHUNK; ++bb) {
        const int b = b0 + bb;
        if (b >= B) break;
        __syncthreads();
        for (int idx = threadIdx.x; idx < SP; idx += 256)
            sdiag[idx] = (idx < S) ? raw_in[(size_t)b * S * S + (size_t)idx * (S + 1)] : 0.f;
        __syncthreads();
        float dv[12];
        #pragma unroll
        for (int q = 0; q < 3; ++q) {
            float4 v = reinterpret_cast<const float4*>(&sdiag[j0])[q];
            dv[4*q] = v.x; dv[4*q+1] = v.y; dv[4*q+2] = v.z; dv[4*q+3] = v.w;
        }
        float4 res; float* rp = &res.x;
        #pragma unroll
        for (int k = 0; k < 4; ++k) {
            float acc = 0.f;
            #pragma unroll
            for (int t = 0; t < UNITS; ++t)
                acc = fmaf(dv[k + t], wv[k * UNITS + t], acc);
            rp[k] = fmaf(acc, (float)UNITS, bias[k]);
        }
        *reinterpret_cast<float4*>(out + (size_t)b * S * S + (size_t)i * S + j0) = res;
    }
}

extern "C" void kernel_launch(void* const* d_in, const int* in_sizes, int n_in,
                              void* d_out, int out_size, void* d_ws, size_t ws_size,
                              hipStream_t stream) {
    const float* in = (const float*)d_in[0];
    const float* w  = (const float*)d_in[1];
    const float* bv = (const float*)d_in[2];
    float* out      = (float*)d_out;

    const int B = in_sizes[0] / (S * S);           // 100
    const int nchunk = (B + BCHUNK - 1) / BCHUNK;  // 10
    dim3 grid((S / 2) * nchunk);                   // 2560 blocks

    if (ws_size >= (size_t)WS_NEED) {
        char* ws = (char*)d_ws;
        float* diag     = (float*)(ws);
        float* w_t      = (float*)(ws + WT_OFF);
        float* bias_sum = (float*)(ws + BIAS_OFF);
        prep_kernel<<<S, 256, 0, stream>>>(w, bv, in, diag, w_t, bias_sum, B);
        cnn_main_kernel<<<grid, 256, 0, stream>>>(w_t, bias_sum, diag, out, B);
    } else {
        cnn_fallback_kernel<<<grid, 256, 0, stream>>>(w, bv, in, out, B);
    }
}